// Round 1
// baseline (550.582 us; speedup 1.0000x reference)
//
#include <hip/hip_runtime.h>
#include <hip/hip_bf16.h>

#define N_ROWS 16384
#define DIN_K  256
#define DOUT_K 64
#define M_COLS 16384
#define LOG2E  1.4426950408889634f

typedef __attribute__((ext_vector_type(8))) short short8;
typedef __attribute__((ext_vector_type(4))) float f32x4;

#define MFMA16 __builtin_amdgcn_mfma_f32_16x16x32_bf16

__device__ inline unsigned short f32_bf16_rne(float x) {
    unsigned u = __builtin_bit_cast(unsigned, x);
    u += 0x7fffu + ((u >> 16) & 1u);
    return (unsigned short)(u >> 16);
}
__device__ inline float bf16_f32(unsigned short h) {
    unsigned u = ((unsigned)h) << 16;
    return __builtin_bit_cast(float, u);
}

// ---------------------------------------------------------------------------
// Kernel 1: before = (X @ W) * log2(e); split to bf16 hi/lo; per-row exp bound
// off2[r] = sum_k max(before_scaled[r][k], 0)  (upper bound of any score*log2e)
// One wave per row: lane = output column k (DOUT=64).
// ---------------------------------------------------------------------------
__global__ __launch_bounds__(256) void k_before(
    const float* __restrict__ X, const float* __restrict__ W,
    float* __restrict__ off2,
    unsigned short* __restrict__ bh, unsigned short* __restrict__ bl)
{
    const int row  = blockIdx.x * 4 + (threadIdx.x >> 6);
    const int lane = threadIdx.x & 63;
    const float* xr = X + (size_t)row * DIN_K;
    float acc = 0.f;
    #pragma unroll 8
    for (int d = 0; d < DIN_K; ++d)
        acc = fmaf(xr[d], W[d * DOUT_K + lane], acc);
    const float bs = acc * LOG2E;
    const unsigned short hs = f32_bf16_rne(bs);
    const float hf = bf16_f32(hs);
    const unsigned short ls = f32_bf16_rne(bs - hf);
    bh[row * DOUT_K + lane] = hs;
    bl[row * DOUT_K + lane] = ls;
    float t = fmaxf(bs, 0.f);
    #pragma unroll
    for (int m = 1; m < 64; m <<= 1) t += __shfl_xor(t, m, 64);
    if (lane == 0) off2[row] = t;
}

// ---------------------------------------------------------------------------
// Kernel 2: pack adjacency A[64][16384] into MFMA B-fragment order, bf16 hi/lo.
// B-frag layout for mfma_f32_16x16x32_bf16: lane l holds
//   B[k = ks*32 + (l>>4)*8 + i][col = chunk*16 + (l&15)], i=0..7 contiguous.
// Packed: [(chunk*2+ks)*64 + lane]*8 + i   (one 16B load per lane in kernel 3)
// ---------------------------------------------------------------------------
__global__ __launch_bounds__(256) void k_pack(
    const float* __restrict__ A,
    unsigned short* __restrict__ ahp, unsigned short* __restrict__ alp)
{
    const int wid   = blockIdx.x * 4 + (threadIdx.x >> 6);  // 0..2047
    const int lane  = threadIdx.x & 63;
    const int chunk = wid >> 1, ks = wid & 1;
    const int col   = chunk * 16 + (lane & 15);
    const int kb    = ks * 32 + ((lane >> 4) * 8);
    const size_t base = ((size_t)(chunk * 2 + ks) * 64 + lane) * 8;
    #pragma unroll
    for (int i = 0; i < 8; ++i) {
        const float a = A[(size_t)(kb + i) * M_COLS + col];
        const unsigned short hs = f32_bf16_rne(a);
        ahp[base + i] = hs;
        alp[base + i] = f32_bf16_rne(a - bf16_f32(hs));
    }
}

// ---------------------------------------------------------------------------
// Kernel 3: fused scores + softmax, two passes over columns, no score storage.
// Block = 8 waves = 512 thr; block owns 64 rows; wave owns 2048 cols.
// Per 16-col chunk: 24 MFMAs (4 row-tiles x 2 k-steps x 3 split terms).
// acc init = -off2[row]   (pass1: l += exp2(acc))
//          = -off2[row] - log2(total)  (pass2: store exp2(acc))
// ---------------------------------------------------------------------------
__global__ __launch_bounds__(512, 2) void k_main(
    const unsigned short* __restrict__ bh, const unsigned short* __restrict__ bl,
    const unsigned short* __restrict__ ahp, const unsigned short* __restrict__ alp,
    const float* __restrict__ off2, float* __restrict__ out)
{
    __shared__ float lds[8][64];
    const int wave = threadIdx.x >> 6;
    const int lane = threadIdx.x & 63;
    const int lrow = lane & 15;   // A-fragment row / C column
    const int lgrp = lane >> 4;   // k-group / C row group
    const int r0   = blockIdx.x * 64;

    // Loop-invariant A-operand fragments (before hi/lo), 64 rows.
    short8 aH[4][2], aL[4][2];
    #pragma unroll
    for (int rt = 0; rt < 4; ++rt)
        #pragma unroll
        for (int ks = 0; ks < 2; ++ks) {
            const size_t o = (size_t)(r0 + rt * 16 + lrow) * DOUT_K + ks * 32 + lgrp * 8;
            aH[rt][ks] = *reinterpret_cast<const short8*>(bh + o);
            aL[rt][ks] = *reinterpret_cast<const short8*>(bl + o);
        }

    float negoff[4][4];
    #pragma unroll
    for (int rt = 0; rt < 4; ++rt)
        #pragma unroll
        for (int q = 0; q < 4; ++q)
            negoff[rt][q] = -off2[r0 + rt * 16 + lgrp * 4 + q];

    float lsum[4][4] = {{0.f}};
    const int cbase = wave * 128;

    // ---- pass 1: denominators ----
    for (int j = 0; j < 128; ++j) {
        const int c = cbase + j;
        const size_t b0 = (size_t)(c * 2) * 512 + lane * 8;
        const short8 bH0 = *reinterpret_cast<const short8*>(ahp + b0);
        const short8 bH1 = *reinterpret_cast<const short8*>(ahp + b0 + 512);
        const short8 bL0 = *reinterpret_cast<const short8*>(alp + b0);
        const short8 bL1 = *reinterpret_cast<const short8*>(alp + b0 + 512);
        #pragma unroll
        for (int rt = 0; rt < 4; ++rt) {
            f32x4 acc = { negoff[rt][0], negoff[rt][1], negoff[rt][2], negoff[rt][3] };
            acc = MFMA16(aH[rt][0], bH0, acc, 0, 0, 0);
            acc = MFMA16(aH[rt][1], bH1, acc, 0, 0, 0);
            acc = MFMA16(aL[rt][0], bH0, acc, 0, 0, 0);
            acc = MFMA16(aL[rt][1], bH1, acc, 0, 0, 0);
            acc = MFMA16(aH[rt][0], bL0, acc, 0, 0, 0);
            acc = MFMA16(aH[rt][1], bL1, acc, 0, 0, 0);
            #pragma unroll
            for (int q = 0; q < 4; ++q) lsum[rt][q] += exp2f(acc[q]);
        }
    }

    // reduce partial sums across the 16 lanes holding the same row
    #pragma unroll
    for (int rt = 0; rt < 4; ++rt)
        #pragma unroll
        for (int q = 0; q < 4; ++q) {
            float v = lsum[rt][q];
            #pragma unroll
            for (int m = 1; m < 16; m <<= 1) v += __shfl_xor(v, m, 64);
            lsum[rt][q] = v;
        }
    if (lrow == 0) {
        #pragma unroll
        for (int rt = 0; rt < 4; ++rt)
            #pragma unroll
            for (int q = 0; q < 4; ++q)
                lds[wave][rt * 16 + lgrp * 4 + q] = lsum[rt][q];
    }
    __syncthreads();

    float base2[4][4];
    #pragma unroll
    for (int rt = 0; rt < 4; ++rt)
        #pragma unroll
        for (int q = 0; q < 4; ++q) {
            const int rl = rt * 16 + lgrp * 4 + q;
            float tot = 0.f;
            #pragma unroll
            for (int w = 0; w < 8; ++w) tot += lds[w][rl];
            base2[rt][q] = negoff[rt][q] - log2f(tot);
        }

    // ---- pass 2: recompute scores, write normalized softmax ----
    for (int j = 0; j < 128; ++j) {
        const int c = cbase + j;
        const size_t b0 = (size_t)(c * 2) * 512 + lane * 8;
        const short8 bH0 = *reinterpret_cast<const short8*>(ahp + b0);
        const short8 bH1 = *reinterpret_cast<const short8*>(ahp + b0 + 512);
        const short8 bL0 = *reinterpret_cast<const short8*>(alp + b0);
        const short8 bL1 = *reinterpret_cast<const short8*>(alp + b0 + 512);
        const int colb = c * 16 + lrow;
        #pragma unroll
        for (int rt = 0; rt < 4; ++rt) {
            f32x4 acc = { base2[rt][0], base2[rt][1], base2[rt][2], base2[rt][3] };
            acc = MFMA16(aH[rt][0], bH0, acc, 0, 0, 0);
            acc = MFMA16(aH[rt][1], bH1, acc, 0, 0, 0);
            acc = MFMA16(aL[rt][0], bH0, acc, 0, 0, 0);
            acc = MFMA16(aL[rt][1], bH1, acc, 0, 0, 0);
            acc = MFMA16(aH[rt][0], bL0, acc, 0, 0, 0);
            acc = MFMA16(aH[rt][1], bL1, acc, 0, 0, 0);
            #pragma unroll
            for (int q = 0; q < 4; ++q) {
                const size_t o = (size_t)(r0 + rt * 16 + lgrp * 4 + q) * M_COLS + colb;
                __builtin_nontemporal_store(exp2f(acc[q]), out + o);
            }
        }
    }
}

extern "C" void kernel_launch(void* const* d_in, const int* in_sizes, int n_in,
                              void* d_out, int out_size, void* d_ws, size_t ws_size,
                              hipStream_t stream) {
    const float* X = (const float*)d_in[0];   // [16384, 256]
    const float* A = (const float*)d_in[1];   // [64, 16384]
    const float* W = (const float*)d_in[2];   // [256, 64]
    float* out = (float*)d_out;               // [16384, 16384]

    char* wsb = (char*)d_ws;
    float*          off2 = (float*)wsb;                                   // 64 KB
    unsigned short* bh   = (unsigned short*)(wsb + (1u << 16));           // 2 MB
    unsigned short* bl   = (unsigned short*)(wsb + (1u << 16) + (1u << 21));
    unsigned short* ahp  = (unsigned short*)(wsb + (1u << 16) + 2u * (1u << 21));
    unsigned short* alp  = (unsigned short*)(wsb + (1u << 16) + 3u * (1u << 21));

    hipLaunchKernelGGL(k_before, dim3(N_ROWS / 4), dim3(256), 0, stream, X, W, off2, bh, bl);
    hipLaunchKernelGGL(k_pack,   dim3(512),        dim3(256), 0, stream, A, ahp, alp);
    hipLaunchKernelGGL(k_main,   dim3(256),        dim3(512), 0, stream, bh, bl, ahp, alp, off2, out);
}